// Round 18
// baseline (337.940 us; speedup 1.0000x reference)
//
#include <hip/hip_runtime.h>
#include <stdint.h>

typedef __attribute__((ext_vector_type(2))) __bf16 bf16x2;
typedef __attribute__((ext_vector_type(4))) __bf16 bf16x4;
typedef __attribute__((ext_vector_type(8))) __bf16 bf16x8;
typedef __attribute__((ext_vector_type(4))) float f32x4;

#define DEV __device__ __forceinline__

DEV void g2lds16(const void* g, void* l) {
  __builtin_amdgcn_global_load_lds(
      (const __attribute__((address_space(1))) void*)g,
      (__attribute__((address_space(3))) void*)l, 16, 0, 0);
}
DEV void bar() {
  asm volatile("" ::: "memory");
  __builtin_amdgcn_s_barrier();
  asm volatile("" ::: "memory");
}
DEV void vm4() { asm volatile("s_waitcnt vmcnt(4)" ::: "memory"); }
DEV void vm0() { asm volatile("s_waitcnt vmcnt(0)" ::: "memory"); }

// ---- f32 -> bf16 vector convert (x) ----
__global__ __launch_bounds__(256) void cvt_f32_bf16(const float* __restrict__ s,
                                                    __bf16* __restrict__ d, int n) {
  int i = (blockIdx.x * 256 + threadIdx.x) * 4;
  if (i >= n) return;
  float4 v = *reinterpret_cast<const float4*>(s + i);
  bf16x4 o;
  o[0] = (__bf16)v.x; o[1] = (__bf16)v.y; o[2] = (__bf16)v.z; o[3] = (__bf16)v.w;
  *reinterpret_cast<bf16x4*>(d + i) = o;
}

// ---- tiled transpose f32[K][N] -> bf16[Npad][K] ----
__global__ __launch_bounds__(256) void transpose_to_bf16(const float* __restrict__ src,
                                                         __bf16* __restrict__ dst,
                                                         int K, int N, int Npad) {
  __shared__ float tile[32][33];
  int n0 = blockIdx.x * 32, k0 = blockIdx.y * 32;
  int tx = threadIdx.x & 31, ty = threadIdx.x >> 5;
#pragma unroll
  for (int j = 0; j < 4; ++j) {
    int k = k0 + ty + j * 8;
    int n = n0 + tx;
    float v = 0.f;
    if (n < N) v = src[(long)k * N + n];
    tile[ty + j * 8][tx] = v;
  }
  __syncthreads();
#pragma unroll
  for (int j = 0; j < 4; ++j) {
    int n = n0 + ty + j * 8;
    int k = k0 + tx;
    if (n < Npad) dst[(long)n * K + k] = (__bf16)tile[tx][ty + j * 8];
  }
}

// ============================================================================
// 128x128 MFMA GEMM, triple-buffered LDS, depth-2 prefetch, counted vmcnt(4).
// 4 waves (2x2), wave-tile 64x64, BK=32. LDS 48KB -> 3 blocks/CU.
// Per iter T: stage tile T+2 -> buf[(T+2)%3]; read+MFMA tile T; vm4 (waits
// tile T+1's stages, issued one full iter ago); barrier certifies T+1.
// Slot swizzle per 8KB tile (512 slots of 16B): slot(row,c) =
//   (row>>1)*8 + (row&1)*4 + ((c+(row>>1))&3)  [bijective, conflict-free]
// ============================================================================
#define STAGE3(BUF, KC)                                              \
  { g2lds16(A + aoffg0 + (KC), &As[BUF][q0 * 8]);                    \
    g2lds16(A + aoffg1 + (KC), &As[BUF][q1 * 8]);                    \
    g2lds16(Wt + boffg0 + (KC), &Bs[BUF][q0 * 8]);                   \
    g2lds16(Wt + boffg1 + (KC), &Bs[BUF][q1 * 8]); }

#define COMPUTE3(CUR)                                                \
  { bf16x8 af[4], bw[4];                                             \
    _Pragma("unroll") for (int i = 0; i < 4; ++i)                    \
        af[i] = *reinterpret_cast<const bf16x8*>(&As[CUR][aoffl[i]]);\
    _Pragma("unroll") for (int n = 0; n < 4; ++n)                    \
        bw[n] = *reinterpret_cast<const bf16x8*>(&Bs[CUR][boffl[n]]);\
    __builtin_amdgcn_s_setprio(1);                                   \
    _Pragma("unroll") for (int i = 0; i < 4; ++i)                    \
      _Pragma("unroll") for (int n = 0; n < 4; ++n)                  \
          acc[i][n] = __builtin_amdgcn_mfma_f32_16x16x32_bf16(       \
              af[i], bw[n], acc[i][n], 0, 0, 0);                     \
    __builtin_amdgcn_s_setprio(0); }

#define ITER3(CUR, STG, KC) \
  STAGE3(STG, KC); COMPUTE3(CUR); vm4(); bar();

template <bool OUT_BF16, int K>
__global__ __launch_bounds__(256, 3) void gemm_p3(const __bf16* __restrict__ A,
                                                  const __bf16* __restrict__ Wt,
                                                  const float* __restrict__ bias,
                                                  void* __restrict__ Cout,
                                                  int Nreal, int ldc, int gx) {
  __shared__ __bf16 As[3][4096];
  __shared__ __bf16 Bs[3][4096];
  const int tid = threadIdx.x;
  const int lane = tid & 63, wid = tid >> 6;

  // T1: XCD-chunked bijective swizzle (gridDim.x % 8 == 0)
  const int nwg = gridDim.x;
  const int orig = blockIdx.x;
  const int wg = ((orig & 7) * (nwg >> 3)) + (orig >> 3);
  const int tm = (wg / gx) * 128, tn = (wg % gx) * 128;

  f32x4 acc[4][4] = {};

  // staging decode: chunk q -> (row, swizzled col-chunk), linear LDS slot q
  const int q0 = tid, q1 = tid + 256;
  const int row0 = ((q0 >> 3) << 1) | ((q0 >> 2) & 1);
  const int c0e = (((q0 & 3) - (q0 >> 3)) & 3) * 8;
  const int row1 = row0 + 64;  // q1 decode simplifies to row0+64, same col
  const long aoffg0 = (long)(tm + row0) * K + c0e;
  const long aoffg1 = (long)(tm + row1) * K + c0e;
  const long boffg0 = (long)(tn + row0) * K + c0e;
  const long boffg1 = (long)(tn + row1) * K + c0e;

  // per-lane read offsets (elements within an 8KB tile)
  const int l15 = lane & 15, cl = lane >> 4;
  int aoffl[4], boffl[4];
#pragma unroll
  for (int mf = 0; mf < 4; ++mf) {
    int row = (wid >> 1) * 64 + mf * 16 + l15;
    aoffl[mf] = (row >> 1) * 64 + (((row & 1) << 2) | ((cl + (row >> 1)) & 3)) * 8;
  }
#pragma unroll
  for (int nf = 0; nf < 4; ++nf) {
    int row = (wid & 1) * 64 + nf * 16 + l15;
    boffl[nf] = (row >> 1) * 64 + (((row & 1) << 2) | ((cl + (row >> 1)) & 3)) * 8;
  }

  constexpr int nt = K >> 5;
  // prologue: stage tiles 0,1; certify tile 0
  STAGE3(0, 0);
  STAGE3(1, 32);
  vm4();
  bar();

  if constexpr (K == 1024) {
    // steady T=0..29 (10 triples), tails T=30 (cur 0), T=31 (cur 1)
#pragma unroll 1
    for (int i = 0; i < 10; ++i) {
      const int kc = (3 * i + 2) << 5;
      ITER3(0, 2, kc);
      ITER3(1, 0, kc + 32);
      ITER3(2, 1, kc + 64);
    }
    COMPUTE3(0); vm0(); bar();
    COMPUTE3(1);
  } else {
    // K==2048: peel T=0,1; triples T=2..61 (20); tails T=62 (cur 2), 63 (cur 0)
    ITER3(0, 2, 64);
    ITER3(1, 0, 96);
#pragma unroll 1
    for (int i = 0; i < 20; ++i) {
      const int kc = (3 * i + 4) << 5;
      ITER3(2, 1, kc);
      ITER3(0, 2, kc + 32);
      ITER3(1, 0, kc + 64);
    }
    COMPUTE3(2); vm0(); bar();
    COMPUTE3(0);
  }

  // epilogue: frag D row=(lane>>4)*4+r, col=lane&15
#pragma unroll
  for (int mf = 0; mf < 4; ++mf) {
    const int rg = tm + (wid >> 1) * 64 + mf * 16 + (lane >> 4) * 4;
#pragma unroll
    for (int nf = 0; nf < 4; ++nf) {
      int col = tn + (wid & 1) * 64 + nf * 16 + l15;
      if (col < Nreal) {
        float bv = bias[col];
#pragma unroll
        for (int r = 0; r < 4; ++r) {
          long row = rg + r;
          float v = acc[mf][nf][r] + bv;
          if (OUT_BF16) ((__bf16*)Cout)[row * (long)ldc + col] = (__bf16)v;
          else          ((float*)Cout)[row * (long)ldc + col] = v;
        }
      }
    }
  }
}

// ---- u = y * sigmoid(in_gate), layout u[b][m][t] ----
__global__ __launch_bounds__(256) void u_kernel(const __bf16* __restrict__ pre,
                                                float* __restrict__ u) {
  int i = blockIdx.x * 8 + (threadIdx.x >> 5);
  int m = threadIdx.x & 31;
  const __bf16* pr = pre + (long)i * 2112;
  float y = (float)pr[m];
  float g = (float)pr[1056 + m];
  float sg = 1.f / (1.f + expf(-g));
  int b = i >> 11, t = i & 2047;
  u[(long)((b * 32) + m) * 2048 + t] = y * sg;
}

// ---- scan: interleaved bf16 (re,im) to ws + Re(s) f32 to d_out ----
__global__ __launch_bounds__(64) void scan_kernel(const float* __restrict__ u,
                                                  const float* __restrict__ a,
                                                  const float* __restrict__ bfr,
                                                  __bf16* __restrict__ s_bf,
                                                  float* __restrict__ s_re) {
  int blk = blockIdx.x;
  int b = blk >> 4, mp = blk & 15;
  int lane = threadIdx.x;
  int mh = lane >> 5, c = lane & 31;
  int m = mp * 2 + mh;
  const float* ub = u + (long)(b * 32 + m) * 2048;
  float decay = expf(-fabsf(a[m]));
  float gr = decay * cosf(bfr[c]);
  float gi = decay * sinf(bfr[c]);
  float sr = 0.f, si = 0.f;
  long base = (long)b * 2048 * 1024 + m * 32 + c;
  for (int t = 0; t < 2048; ++t) {
    float uv = ub[t];
    float nr = fmaf(gr, sr, fmaf(-gi, si, uv));
    float ni_ = fmaf(gr, si, gi * sr);
    sr = nr; si = ni_;
    long ci = base + (long)t * 1024;
    bf16x2 zv; zv[0] = (__bf16)sr; zv[1] = (__bf16)si;
    *reinterpret_cast<bf16x2*>(s_bf + 2 * ci) = zv;
    s_re[ci] = sr;
  }
}

// ---- layernorm + gated mix: vectorized, in place on f32 z rows ----
__global__ __launch_bounds__(256) void ln_gate_kernel(float* __restrict__ z,
                                                      const __bf16* __restrict__ pre) {
  __shared__ float rs[4], rss[4];
  long row = blockIdx.x;
  float* zp = z + row * 1024;
  int tid = threadIdx.x;
  float4 v = *reinterpret_cast<const float4*>(zp + tid * 4);
  float s = v.x + v.y + v.z + v.w;
  float ss = v.x * v.x + v.y * v.y + v.z * v.z + v.w * v.w;
#pragma unroll
  for (int o = 32; o > 0; o >>= 1) {
    s += __shfl_down(s, o, 64);
    ss += __shfl_down(ss, o, 64);
  }
  if ((tid & 63) == 0) { rs[tid >> 6] = s; rss[tid >> 6] = ss; }
  __syncthreads();
  s = rs[0] + rs[1] + rs[2] + rs[3];
  ss = rss[0] + rss[1] + rss[2] + rss[3];
  float mean = s * (1.f / 1024.f);
  float var = ss * (1.f / 1024.f) - mean * mean;
  float rstd = rsqrtf(var + 1e-5f);
  const __bf16* pr = pre + row * 2112;
  bf16x4 th = *reinterpret_cast<const bf16x4*>(pr + 32 + tid * 4);
  bf16x4 og = *reinterpret_cast<const bf16x4*>(pr + 1088 + tid * 4);
  float4 o; float g;
  g = 1.f / (1.f + expf(-(float)og[0])); o.x = (v.x - mean) * rstd * g + (float)th[0] * (1.f - g);
  g = 1.f / (1.f + expf(-(float)og[1])); o.y = (v.y - mean) * rstd * g + (float)th[1] * (1.f - g);
  g = 1.f / (1.f + expf(-(float)og[2])); o.z = (v.z - mean) * rstd * g + (float)th[2] * (1.f - g);
  g = 1.f / (1.f + expf(-(float)og[3])); o.w = (v.w - mean) * rstd * g + (float)th[3] * (1.f - g);
  *reinterpret_cast<float4*>(zp + tid * 4) = o;
}

extern "C" void kernel_launch(void* const* d_in, const int* in_sizes, int n_in,
                              void* d_out, int out_size, void* d_ws, size_t ws_size,
                              hipStream_t stream) {
  const float* x = (const float*)d_in[0];
  const float* pre_w = (const float*)d_in[1];
  const float* pre_b = (const float*)d_in[2];
  const float* mix_w = (const float*)d_in[3];
  const float* mix_b = (const float*)d_in[4];
  const float* a = (const float*)d_in[5];
  const float* bfr = (const float*)d_in[6];

  // ws: buf0 (x_bf -> s_bf) | wtbuf (preWT then mixWT) | pre | u
  char* ws = (char*)d_ws;
  __bf16* buf0  = (__bf16*)(ws + 0);           // 67,108,864 B
  __bf16* wtbuf = (__bf16*)(ws + 67108864);    //  4,718,592 B (max [2304][1024])
  __bf16* pre   = (__bf16*)(ws + 71827456);    // 69,206,016 B [16384][2112]
  float*  u     = (float*)(ws + 141033472);    //  2,097,152 B
  const size_t WS_NEEDED = 143130624ull;       // < proven 147,062,784
  if (ws_size < WS_NEEDED) return;

  __bf16* x_bf = buf0;
  __bf16* s_bf = buf0;

  float* out0 = (float*)d_out;                 // f32 [16384][1024]
  float* s_re = out0 + 16777216;               // f32 Re(s)

  cvt_f32_bf16<<<16384, 256, 0, stream>>>(x, x_bf, 16777216);
  transpose_to_bf16<<<dim3(68, 32), 256, 0, stream>>>(pre_w, wtbuf, 1024, 2112, 2176);
  gemm_p3<true, 1024><<<2176, 256, 0, stream>>>(x_bf, wtbuf, pre_b, pre,
                                                2112, 2112, 17);
  u_kernel<<<2048, 256, 0, stream>>>(pre, u);
  transpose_to_bf16<<<dim3(32, 64), 256, 0, stream>>>(mix_w, wtbuf, 2048, 1024, 1024);
  scan_kernel<<<128, 64, 0, stream>>>(u, a, bfr, s_bf, s_re);  // overwrites x_bf
  gemm_p3<false, 2048><<<1024, 256, 0, stream>>>(s_bf, wtbuf, mix_b, out0,
                                                 1024, 1024, 8);
  ln_gate_kernel<<<16384, 256, 0, stream>>>(out0, pre);
}

// Round 19
// 333.686 us; speedup vs baseline: 1.0127x; 1.0127x over previous
//
#include <hip/hip_runtime.h>
#include <stdint.h>

typedef __attribute__((ext_vector_type(2))) __bf16 bf16x2;
typedef __attribute__((ext_vector_type(4))) __bf16 bf16x4;
typedef __attribute__((ext_vector_type(8))) __bf16 bf16x8;
typedef __attribute__((ext_vector_type(4))) float f32x4;

#define DEV __device__ __forceinline__

DEV void g2lds16(const void* g, void* l) {
  __builtin_amdgcn_global_load_lds(
      (const __attribute__((address_space(1))) void*)g,
      (__attribute__((address_space(3))) void*)l, 16, 0, 0);
}
DEV void bar() {
  asm volatile("" ::: "memory");
  __builtin_amdgcn_s_barrier();
  asm volatile("" ::: "memory");
}
DEV void vm4() { asm volatile("s_waitcnt vmcnt(4)" ::: "memory"); }
DEV void vm0() { asm volatile("s_waitcnt vmcnt(0)" ::: "memory"); }

// ---- f32 -> bf16 vector convert (x) ----
__global__ __launch_bounds__(256) void cvt_f32_bf16(const float* __restrict__ s,
                                                    __bf16* __restrict__ d, int n) {
  int i = (blockIdx.x * 256 + threadIdx.x) * 4;
  if (i >= n) return;
  float4 v = *reinterpret_cast<const float4*>(s + i);
  bf16x4 o;
  o[0] = (__bf16)v.x; o[1] = (__bf16)v.y; o[2] = (__bf16)v.z; o[3] = (__bf16)v.w;
  *reinterpret_cast<bf16x4*>(d + i) = o;
}

// ---- tiled transpose f32[K][N] -> bf16[Npad][K] ----
__global__ __launch_bounds__(256) void transpose_to_bf16(const float* __restrict__ src,
                                                         __bf16* __restrict__ dst,
                                                         int K, int N, int Npad) {
  __shared__ float tile[32][33];
  int n0 = blockIdx.x * 32, k0 = blockIdx.y * 32;
  int tx = threadIdx.x & 31, ty = threadIdx.x >> 5;
#pragma unroll
  for (int j = 0; j < 4; ++j) {
    int k = k0 + ty + j * 8;
    int n = n0 + tx;
    float v = 0.f;
    if (n < N) v = src[(long)k * N + n];
    tile[ty + j * 8][tx] = v;
  }
  __syncthreads();
#pragma unroll
  for (int j = 0; j < 4; ++j) {
    int n = n0 + ty + j * 8;
    int k = k0 + tx;
    if (n < Npad) dst[(long)n * K + k] = (__bf16)tile[tx][ty + j * 8];
  }
}

// ============================================================================
// 128x128 MFMA GEMM, triple-buffered LDS, depth-2 prefetch, counted vmcnt(4).
// (unchanged from round 18 — 103 us, MfmaUtil 30%, conflicts 0, FETCH ideal)
// ============================================================================
#define STAGE3(BUF, KC)                                              \
  { g2lds16(A + aoffg0 + (KC), &As[BUF][q0 * 8]);                    \
    g2lds16(A + aoffg1 + (KC), &As[BUF][q1 * 8]);                    \
    g2lds16(Wt + boffg0 + (KC), &Bs[BUF][q0 * 8]);                   \
    g2lds16(Wt + boffg1 + (KC), &Bs[BUF][q1 * 8]); }

#define COMPUTE3(CUR)                                                \
  { bf16x8 af[4], bw[4];                                             \
    _Pragma("unroll") for (int i = 0; i < 4; ++i)                    \
        af[i] = *reinterpret_cast<const bf16x8*>(&As[CUR][aoffl[i]]);\
    _Pragma("unroll") for (int n = 0; n < 4; ++n)                    \
        bw[n] = *reinterpret_cast<const bf16x8*>(&Bs[CUR][boffl[n]]);\
    __builtin_amdgcn_s_setprio(1);                                   \
    _Pragma("unroll") for (int i = 0; i < 4; ++i)                    \
      _Pragma("unroll") for (int n = 0; n < 4; ++n)                  \
          acc[i][n] = __builtin_amdgcn_mfma_f32_16x16x32_bf16(       \
              af[i], bw[n], acc[i][n], 0, 0, 0);                     \
    __builtin_amdgcn_s_setprio(0); }

#define ITER3(CUR, STG, KC) \
  STAGE3(STG, KC); COMPUTE3(CUR); vm4(); bar();

template <bool OUT_BF16, int K>
__global__ __launch_bounds__(256, 3) void gemm_p3(const __bf16* __restrict__ A,
                                                  const __bf16* __restrict__ Wt,
                                                  const float* __restrict__ bias,
                                                  void* __restrict__ Cout,
                                                  int Nreal, int ldc, int gx) {
  __shared__ __bf16 As[3][4096];
  __shared__ __bf16 Bs[3][4096];
  const int tid = threadIdx.x;
  const int lane = tid & 63, wid = tid >> 6;

  const int nwg = gridDim.x;
  const int orig = blockIdx.x;
  const int wg = ((orig & 7) * (nwg >> 3)) + (orig >> 3);
  const int tm = (wg / gx) * 128, tn = (wg % gx) * 128;

  f32x4 acc[4][4] = {};

  const int q0 = tid, q1 = tid + 256;
  const int row0 = ((q0 >> 3) << 1) | ((q0 >> 2) & 1);
  const int c0e = (((q0 & 3) - (q0 >> 3)) & 3) * 8;
  const int row1 = row0 + 64;
  const long aoffg0 = (long)(tm + row0) * K + c0e;
  const long aoffg1 = (long)(tm + row1) * K + c0e;
  const long boffg0 = (long)(tn + row0) * K + c0e;
  const long boffg1 = (long)(tn + row1) * K + c0e;

  const int l15 = lane & 15, cl = lane >> 4;
  int aoffl[4], boffl[4];
#pragma unroll
  for (int mf = 0; mf < 4; ++mf) {
    int row = (wid >> 1) * 64 + mf * 16 + l15;
    aoffl[mf] = (row >> 1) * 64 + (((row & 1) << 2) | ((cl + (row >> 1)) & 3)) * 8;
  }
#pragma unroll
  for (int nf = 0; nf < 4; ++nf) {
    int row = (wid & 1) * 64 + nf * 16 + l15;
    boffl[nf] = (row >> 1) * 64 + (((row & 1) << 2) | ((cl + (row >> 1)) & 3)) * 8;
  }

  STAGE3(0, 0);
  STAGE3(1, 32);
  vm4();
  bar();

  if constexpr (K == 1024) {
#pragma unroll 1
    for (int i = 0; i < 10; ++i) {
      const int kc = (3 * i + 2) << 5;
      ITER3(0, 2, kc);
      ITER3(1, 0, kc + 32);
      ITER3(2, 1, kc + 64);
    }
    COMPUTE3(0); vm0(); bar();
    COMPUTE3(1);
  } else {
    ITER3(0, 2, 64);
    ITER3(1, 0, 96);
#pragma unroll 1
    for (int i = 0; i < 20; ++i) {
      const int kc = (3 * i + 4) << 5;
      ITER3(2, 1, kc);
      ITER3(0, 2, kc + 32);
      ITER3(1, 0, kc + 64);
    }
    COMPUTE3(2); vm0(); bar();
    COMPUTE3(0);
  }

#pragma unroll
  for (int mf = 0; mf < 4; ++mf) {
    const int rg = tm + (wid >> 1) * 64 + mf * 16 + (lane >> 4) * 4;
#pragma unroll
    for (int nf = 0; nf < 4; ++nf) {
      int col = tn + (wid & 1) * 64 + nf * 16 + l15;
      if (col < Nreal) {
        float bv = bias[col];
#pragma unroll
        for (int r = 0; r < 4; ++r) {
          long row = rg + r;
          float v = acc[mf][nf][r] + bv;
          if (OUT_BF16) ((__bf16*)Cout)[row * (long)ldc + col] = (__bf16)v;
          else          ((float*)Cout)[row * (long)ldc + col] = v;
        }
      }
    }
  }
}

// ---- u = y * sigmoid(in_gate), COALESCED via LDS transpose ----
// grid: 8(b) x 32(t-chunk of 64) = 256 blocks, 256 threads.
__global__ __launch_bounds__(256) void u_kernel(const __bf16* __restrict__ pre,
                                                float* __restrict__ u) {
  __shared__ float su[64][33];
  const int b = blockIdx.x >> 5;
  const int t0 = (blockIdx.x & 31) * 64;
  const int tid = threadIdx.x;
  {
    const int r = tid >> 2;            // row within chunk 0..63
    const int j = (tid & 3) * 8;       // m base 0,8,16,24
    const long rowoff = (long)(b * 2048 + t0 + r) * 2112;
    bf16x8 y8 = *reinterpret_cast<const bf16x8*>(pre + rowoff + j);
    bf16x8 g8 = *reinterpret_cast<const bf16x8*>(pre + rowoff + 1056 + j);
#pragma unroll
    for (int k = 0; k < 8; ++k) {
      float y = (float)y8[k];
      float g = (float)g8[k];
      su[r][j + k] = y / (1.f + expf(-g));
    }
  }
  __syncthreads();
  {
    const int m = tid >> 3;            // 0..31
    const int tt = (tid & 7) * 8;      // 0..56
    float4 o0, o1;
    o0.x = su[tt + 0][m]; o0.y = su[tt + 1][m];
    o0.z = su[tt + 2][m]; o0.w = su[tt + 3][m];
    o1.x = su[tt + 4][m]; o1.y = su[tt + 5][m];
    o1.z = su[tt + 6][m]; o1.w = su[tt + 7][m];
    float* up = u + ((long)(b * 32 + m) * 2048 + t0 + tt);
    *reinterpret_cast<float4*>(up) = o0;
    *reinterpret_cast<float4*>(up + 4) = o1;
  }
}

// ---- scan: interleaved bf16 (re,im) to ws + Re(s) f32 to d_out ----
__global__ __launch_bounds__(64) void scan_kernel(const float* __restrict__ u,
                                                  const float* __restrict__ a,
                                                  const float* __restrict__ bfr,
                                                  __bf16* __restrict__ s_bf,
                                                  float* __restrict__ s_re) {
  int blk = blockIdx.x;
  int b = blk >> 4, mp = blk & 15;
  int lane = threadIdx.x;
  int mh = lane >> 5, c = lane & 31;
  int m = mp * 2 + mh;
  const float* ub = u + (long)(b * 32 + m) * 2048;
  float decay = expf(-fabsf(a[m]));
  float gr = decay * cosf(bfr[c]);
  float gi = decay * sinf(bfr[c]);
  float sr = 0.f, si = 0.f;
  long base = (long)b * 2048 * 1024 + m * 32 + c;
  for (int t = 0; t < 2048; ++t) {
    float uv = ub[t];
    float nr = fmaf(gr, sr, fmaf(-gi, si, uv));
    float ni_ = fmaf(gr, si, gi * sr);
    sr = nr; si = ni_;
    long ci = base + (long)t * 1024;
    bf16x2 zv; zv[0] = (__bf16)sr; zv[1] = (__bf16)si;
    *reinterpret_cast<bf16x2*>(s_bf + 2 * ci) = zv;
    s_re[ci] = sr;
  }
}

// ---- layernorm + gated mix: z bf16 in -> f32 out ----
__global__ __launch_bounds__(256) void ln_gate_kernel(const __bf16* __restrict__ zb,
                                                      float* __restrict__ out,
                                                      const __bf16* __restrict__ pre) {
  __shared__ float rs[4], rss[4];
  long row = blockIdx.x;
  const __bf16* zp = zb + row * 1024;
  int tid = threadIdx.x;
  bf16x4 zv4 = *reinterpret_cast<const bf16x4*>(zp + tid * 4);
  float v0 = (float)zv4[0], v1 = (float)zv4[1], v2 = (float)zv4[2], v3 = (float)zv4[3];
  float s = v0 + v1 + v2 + v3;
  float ss = v0 * v0 + v1 * v1 + v2 * v2 + v3 * v3;
#pragma unroll
  for (int o = 32; o > 0; o >>= 1) {
    s += __shfl_down(s, o, 64);
    ss += __shfl_down(ss, o, 64);
  }
  if ((tid & 63) == 0) { rs[tid >> 6] = s; rss[tid >> 6] = ss; }
  __syncthreads();
  s = rs[0] + rs[1] + rs[2] + rs[3];
  ss = rss[0] + rss[1] + rss[2] + rss[3];
  float mean = s * (1.f / 1024.f);
  float var = ss * (1.f / 1024.f) - mean * mean;
  float rstd = rsqrtf(var + 1e-5f);
  const __bf16* pr = pre + row * 2112;
  bf16x4 th = *reinterpret_cast<const bf16x4*>(pr + 32 + tid * 4);
  bf16x4 og = *reinterpret_cast<const bf16x4*>(pr + 1088 + tid * 4);
  float4 o; float g;
  g = 1.f / (1.f + expf(-(float)og[0])); o.x = (v0 - mean) * rstd * g + (float)th[0] * (1.f - g);
  g = 1.f / (1.f + expf(-(float)og[1])); o.y = (v1 - mean) * rstd * g + (float)th[1] * (1.f - g);
  g = 1.f / (1.f + expf(-(float)og[2])); o.z = (v2 - mean) * rstd * g + (float)th[2] * (1.f - g);
  g = 1.f / (1.f + expf(-(float)og[3])); o.w = (v3 - mean) * rstd * g + (float)th[3] * (1.f - g);
  *reinterpret_cast<float4*>(out + row * 1024 + tid * 4) = o;
}

extern "C" void kernel_launch(void* const* d_in, const int* in_sizes, int n_in,
                              void* d_out, int out_size, void* d_ws, size_t ws_size,
                              hipStream_t stream) {
  const float* x = (const float*)d_in[0];
  const float* pre_w = (const float*)d_in[1];
  const float* pre_b = (const float*)d_in[2];
  const float* mix_w = (const float*)d_in[3];
  const float* mix_b = (const float*)d_in[4];
  const float* a = (const float*)d_in[5];
  const float* bfr = (const float*)d_in[6];

  // ws (176,685,056 B; ws_size >= 180,617,216 proven by round-5 guard):
  char* ws = (char*)d_ws;
  __bf16* buf0  = (__bf16*)(ws + 0);           // 67,108,864 B (x_bf -> s_bf)
  __bf16* wtbuf = (__bf16*)(ws + 67108864);    //  4,718,592 B
  __bf16* pre   = (__bf16*)(ws + 71827456);    // 69,206,016 B [16384][2112]
  float*  u     = (float*)(ws + 141033472);    //  2,097,152 B
  __bf16* z_bf  = (__bf16*)(ws + 143130624);   // 33,554,432 B [16384][1024]
  const size_t WS_NEEDED = 176685056ull;
  if (ws_size < WS_NEEDED) return;

  __bf16* x_bf = buf0;
  __bf16* s_bf = buf0;

  float* out0 = (float*)d_out;                 // f32 [16384][1024]
  float* s_re = out0 + 16777216;               // f32 Re(s)

  cvt_f32_bf16<<<16384, 256, 0, stream>>>(x, x_bf, 16777216);
  transpose_to_bf16<<<dim3(68, 32), 256, 0, stream>>>(pre_w, wtbuf, 1024, 2112, 2176);
  gemm_p3<true, 1024><<<2176, 256, 0, stream>>>(x_bf, wtbuf, pre_b, pre,
                                                2112, 2112, 17);
  u_kernel<<<256, 256, 0, stream>>>(pre, u);
  transpose_to_bf16<<<dim3(32, 64), 256, 0, stream>>>(mix_w, wtbuf, 2048, 1024, 1024);
  scan_kernel<<<128, 64, 0, stream>>>(u, a, bfr, s_bf, s_re);  // overwrites x_bf
  gemm_p3<true, 2048><<<1024, 256, 0, stream>>>(s_bf, wtbuf, mix_b, z_bf,
                                                1024, 1024, 8);
  ln_gate_kernel<<<16384, 256, 0, stream>>>(z_bf, out0, pre);
}

// Round 20
// 320.403 us; speedup vs baseline: 1.0547x; 1.0415x over previous
//
#include <hip/hip_runtime.h>
#include <stdint.h>

typedef __attribute__((ext_vector_type(2))) __bf16 bf16x2;
typedef __attribute__((ext_vector_type(4))) __bf16 bf16x4;
typedef __attribute__((ext_vector_type(8))) __bf16 bf16x8;
typedef __attribute__((ext_vector_type(4))) float f32x4;

#define DEV __device__ __forceinline__

DEV void g2lds16(const void* g, void* l) {
  __builtin_amdgcn_global_load_lds(
      (const __attribute__((address_space(1))) void*)g,
      (__attribute__((address_space(3))) void*)l, 16, 0, 0);
}
DEV void bar() {
  asm volatile("" ::: "memory");
  __builtin_amdgcn_s_barrier();
  asm volatile("" ::: "memory");
}
DEV void vm6() { asm volatile("s_waitcnt vmcnt(6)" ::: "memory"); }
DEV void vm0() { asm volatile("s_waitcnt vmcnt(0)" ::: "memory"); }

// ---- f32 -> bf16 vector convert (x) ----
__global__ __launch_bounds__(256) void cvt_f32_bf16(const float* __restrict__ s,
                                                    __bf16* __restrict__ d, int n) {
  int i = (blockIdx.x * 256 + threadIdx.x) * 4;
  if (i >= n) return;
  float4 v = *reinterpret_cast<const float4*>(s + i);
  bf16x4 o;
  o[0] = (__bf16)v.x; o[1] = (__bf16)v.y; o[2] = (__bf16)v.z; o[3] = (__bf16)v.w;
  *reinterpret_cast<bf16x4*>(d + i) = o;
}

// ---- tiled transpose f32[K][N] -> bf16[Npad][K] ----
__global__ __launch_bounds__(256) void transpose_to_bf16(const float* __restrict__ src,
                                                         __bf16* __restrict__ dst,
                                                         int K, int N, int Npad) {
  __shared__ float tile[32][33];
  int n0 = blockIdx.x * 32, k0 = blockIdx.y * 32;
  int tx = threadIdx.x & 31, ty = threadIdx.x >> 5;
#pragma unroll
  for (int j = 0; j < 4; ++j) {
    int k = k0 + ty + j * 8;
    int n = n0 + tx;
    float v = 0.f;
    if (n < N) v = src[(long)k * N + n];
    tile[ty + j * 8][tx] = v;
  }
  __syncthreads();
#pragma unroll
  for (int j = 0; j < 4; ++j) {
    int n = n0 + ty + j * 8;
    int k = k0 + tx;
    if (n < Npad) dst[(long)n * K + k] = (__bf16)tile[tx][ty + j * 8];
  }
}

// ============================================================================
// 256x128 MFMA GEMM: 4 waves (2M x 2N), wave-tile 128x64 (acc[8][4]), BK=32.
// Triple-buffered LDS (72KB -> 2 blocks/CU), depth-2 prefetch, counted vm6.
// Per iter/wave: 32 MFMA vs 12KB LDS reads (375B/MFMA vs 512 at 64x64).
// Slot swizzle per tile: slot(row,c) = (row>>1)*8+((row&1)<<2)+((c+(row>>1))&3)
// (bijective, 2-way banks on reads = free; staging writes linear 16B/lane).
// ============================================================================
#define STAGE6(BUF, KC)                                                  \
  { g2lds16(A + aoffg0 + (KC), &As[BUF][q0 * 8]);                        \
    g2lds16(A + aoffg0 + 64 * (long)K + (KC), &As[BUF][(q0 + 256) * 8]); \
    g2lds16(A + aoffg0 + 128 * (long)K + (KC), &As[BUF][(q0 + 512) * 8]);\
    g2lds16(A + aoffg0 + 192 * (long)K + (KC), &As[BUF][(q0 + 768) * 8]);\
    g2lds16(Wt + boffg0 + (KC), &Bs[BUF][q0 * 8]);                       \
    g2lds16(Wt + boffg0 + 64 * (long)K + (KC), &Bs[BUF][(q0 + 256) * 8]); }

#define COMPUTE6(CUR)                                                \
  { bf16x8 af[8], bw[4];                                             \
    _Pragma("unroll") for (int i = 0; i < 8; ++i)                    \
        af[i] = *reinterpret_cast<const bf16x8*>(&As[CUR][aoffl[i]]);\
    _Pragma("unroll") for (int n = 0; n < 4; ++n)                    \
        bw[n] = *reinterpret_cast<const bf16x8*>(&Bs[CUR][boffl[n]]);\
    __builtin_amdgcn_s_setprio(1);                                   \
    _Pragma("unroll") for (int i = 0; i < 8; ++i)                    \
      _Pragma("unroll") for (int n = 0; n < 4; ++n)                  \
          acc[i][n] = __builtin_amdgcn_mfma_f32_16x16x32_bf16(       \
              af[i], bw[n], acc[i][n], 0, 0, 0);                     \
    __builtin_amdgcn_s_setprio(0); }

#define ITER6(CUR, STG, KC) \
  STAGE6(STG, KC); COMPUTE6(CUR); vm6(); bar();

template <bool OUT_BF16, int K>
__global__ __launch_bounds__(256, 2) void gemm_w2(const __bf16* __restrict__ A,
                                                  const __bf16* __restrict__ Wt,
                                                  const float* __restrict__ bias,
                                                  void* __restrict__ Cout,
                                                  int Nreal, int ldc, int gx) {
  __shared__ __bf16 As[3][8192];   // 256 x 32 per buffer (16KB)
  __shared__ __bf16 Bs[3][4096];   // 128 x 32 per buffer (8KB)
  const int tid = threadIdx.x;
  const int lane = tid & 63, wid = tid >> 6;
  const int wm = wid >> 1, wn = wid & 1;  // 2M x 2N waves

  // T1: XCD-chunked bijective swizzle (gridDim.x % 8 == 0)
  const int nwg = gridDim.x;
  const int orig = blockIdx.x;
  const int wg = ((orig & 7) * (nwg >> 3)) + (orig >> 3);
  const int tm = (wg / gx) * 256, tn = (wg % gx) * 128;

  f32x4 acc[8][4] = {};

  // staging decode: chunk q -> (row, swizzled col-chunk); LDS slot q linear.
  const int q0 = tid;
  const int row0 = ((q0 >> 3) << 1) | ((q0 >> 2) & 1);
  const int c0e = (((q0 & 3) - (q0 >> 3)) & 3) * 8;
  const long aoffg0 = (long)(tm + row0) * K + c0e;
  const long boffg0 = (long)(tn + row0) * K + c0e;

  // per-lane read offsets (elements within a tile buffer)
  const int l15 = lane & 15, cl = lane >> 4;
  int aoffl[8], boffl[4];
#pragma unroll
  for (int mf = 0; mf < 8; ++mf) {
    int row = wm * 128 + mf * 16 + l15;
    aoffl[mf] = (row >> 1) * 64 + (((row & 1) << 2) | ((cl + (row >> 1)) & 3)) * 8;
  }
#pragma unroll
  for (int nf = 0; nf < 4; ++nf) {
    int row = wn * 64 + nf * 16 + l15;
    boffl[nf] = (row >> 1) * 64 + (((row & 1) << 2) | ((cl + (row >> 1)) & 3)) * 8;
  }

  // prologue: stage tiles 0,1; certify tile 0
  STAGE6(0, 0);
  STAGE6(1, 32);
  vm6();
  bar();

  if constexpr (K == 1024) {
    // nt=32: 10 triples (i=0..29), tails 30 (cur 0), 31 (cur 1)
#pragma unroll 1
    for (int i = 0; i < 10; ++i) {
      const int kc = (3 * i + 2) << 5;
      ITER6(0, 2, kc);
      ITER6(1, 0, kc + 32);
      ITER6(2, 1, kc + 64);
    }
    COMPUTE6(0); vm0(); bar();
    COMPUTE6(1);
  } else {
    // nt=64: peel 2, 20 triples, tails 62 (cur 2), 63 (cur 0)
    ITER6(0, 2, 64);
    ITER6(1, 0, 96);
#pragma unroll 1
    for (int i = 0; i < 20; ++i) {
      const int kc = (3 * i + 4) << 5;
      ITER6(2, 1, kc);
      ITER6(0, 2, kc + 32);
      ITER6(1, 0, kc + 64);
    }
    COMPUTE6(2); vm0(); bar();
    COMPUTE6(0);
  }

  // epilogue: frag D row=(lane>>4)*4+r, col=lane&15
#pragma unroll
  for (int mf = 0; mf < 8; ++mf) {
    const int rg = tm + wm * 128 + mf * 16 + (lane >> 4) * 4;
#pragma unroll
    for (int nf = 0; nf < 4; ++nf) {
      int col = tn + wn * 64 + nf * 16 + l15;
      if (col < Nreal) {
        float bv = bias[col];
#pragma unroll
        for (int r = 0; r < 4; ++r) {
          long row = rg + r;
          float v = acc[mf][nf][r] + bv;
          if (OUT_BF16) ((__bf16*)Cout)[row * (long)ldc + col] = (__bf16)v;
          else          ((float*)Cout)[row * (long)ldc + col] = v;
        }
      }
    }
  }
}

// ---- u = y * sigmoid(in_gate), coalesced via LDS transpose ----
__global__ __launch_bounds__(256) void u_kernel(const __bf16* __restrict__ pre,
                                                float* __restrict__ u) {
  __shared__ float su[64][33];
  const int b = blockIdx.x >> 5;
  const int t0 = (blockIdx.x & 31) * 64;
  const int tid = threadIdx.x;
  {
    const int r = tid >> 2;
    const int j = (tid & 3) * 8;
    const long rowoff = (long)(b * 2048 + t0 + r) * 2112;
    bf16x8 y8 = *reinterpret_cast<const bf16x8*>(pre + rowoff + j);
    bf16x8 g8 = *reinterpret_cast<const bf16x8*>(pre + rowoff + 1056 + j);
#pragma unroll
    for (int k = 0; k < 8; ++k) {
      float y = (float)y8[k];
      float g = (float)g8[k];
      su[r][j + k] = y / (1.f + expf(-g));
    }
  }
  __syncthreads();
  {
    const int m = tid >> 3;
    const int tt = (tid & 7) * 8;
    float4 o0, o1;
    o0.x = su[tt + 0][m]; o0.y = su[tt + 1][m];
    o0.z = su[tt + 2][m]; o0.w = su[tt + 3][m];
    o1.x = su[tt + 4][m]; o1.y = su[tt + 5][m];
    o1.z = su[tt + 6][m]; o1.w = su[tt + 7][m];
    float* up = u + ((long)(b * 32 + m) * 2048 + t0 + tt);
    *reinterpret_cast<float4*>(up) = o0;
    *reinterpret_cast<float4*>(up + 4) = o1;
  }
}

// ---- scan: interleaved bf16 (re,im) to ws + Re(s) f32 to d_out ----
__global__ __launch_bounds__(64) void scan_kernel(const float* __restrict__ u,
                                                  const float* __restrict__ a,
                                                  const float* __restrict__ bfr,
                                                  __bf16* __restrict__ s_bf,
                                                  float* __restrict__ s_re) {
  int blk = blockIdx.x;
  int b = blk >> 4, mp = blk & 15;
  int lane = threadIdx.x;
  int mh = lane >> 5, c = lane & 31;
  int m = mp * 2 + mh;
  const float* ub = u + (long)(b * 32 + m) * 2048;
  float decay = expf(-fabsf(a[m]));
  float gr = decay * cosf(bfr[c]);
  float gi = decay * sinf(bfr[c]);
  float sr = 0.f, si = 0.f;
  long base = (long)b * 2048 * 1024 + m * 32 + c;
  for (int t = 0; t < 2048; ++t) {
    float uv = ub[t];
    float nr = fmaf(gr, sr, fmaf(-gi, si, uv));
    float ni_ = fmaf(gr, si, gi * sr);
    sr = nr; si = ni_;
    long ci = base + (long)t * 1024;
    bf16x2 zv; zv[0] = (__bf16)sr; zv[1] = (__bf16)si;
    *reinterpret_cast<bf16x2*>(s_bf + 2 * ci) = zv;
    s_re[ci] = sr;
  }
}

// ---- layernorm + gated mix: z bf16 in -> f32 out ----
__global__ __launch_bounds__(256) void ln_gate_kernel(const __bf16* __restrict__ zb,
                                                      float* __restrict__ out,
                                                      const __bf16* __restrict__ pre) {
  __shared__ float rs[4], rss[4];
  long row = blockIdx.x;
  const __bf16* zp = zb + row * 1024;
  int tid = threadIdx.x;
  bf16x4 zv4 = *reinterpret_cast<const bf16x4*>(zp + tid * 4);
  float v0 = (float)zv4[0], v1 = (float)zv4[1], v2 = (float)zv4[2], v3 = (float)zv4[3];
  float s = v0 + v1 + v2 + v3;
  float ss = v0 * v0 + v1 * v1 + v2 * v2 + v3 * v3;
#pragma unroll
  for (int o = 32; o > 0; o >>= 1) {
    s += __shfl_down(s, o, 64);
    ss += __shfl_down(ss, o, 64);
  }
  if ((tid & 63) == 0) { rs[tid >> 6] = s; rss[tid >> 6] = ss; }
  __syncthreads();
  s = rs[0] + rs[1] + rs[2] + rs[3];
  ss = rss[0] + rss[1] + rss[2] + rss[3];
  float mean = s * (1.f / 1024.f);
  float var = ss * (1.f / 1024.f) - mean * mean;
  float rstd = rsqrtf(var + 1e-5f);
  const __bf16* pr = pre + row * 2112;
  bf16x4 th = *reinterpret_cast<const bf16x4*>(pr + 32 + tid * 4);
  bf16x4 og = *reinterpret_cast<const bf16x4*>(pr + 1088 + tid * 4);
  float4 o; float g;
  g = 1.f / (1.f + expf(-(float)og[0])); o.x = (v0 - mean) * rstd * g + (float)th[0] * (1.f - g);
  g = 1.f / (1.f + expf(-(float)og[1])); o.y = (v1 - mean) * rstd * g + (float)th[1] * (1.f - g);
  g = 1.f / (1.f + expf(-(float)og[2])); o.z = (v2 - mean) * rstd * g + (float)th[2] * (1.f - g);
  g = 1.f / (1.f + expf(-(float)og[3])); o.w = (v3 - mean) * rstd * g + (float)th[3] * (1.f - g);
  *reinterpret_cast<float4*>(out + row * 1024 + tid * 4) = o;
}

extern "C" void kernel_launch(void* const* d_in, const int* in_sizes, int n_in,
                              void* d_out, int out_size, void* d_ws, size_t ws_size,
                              hipStream_t stream) {
  const float* x = (const float*)d_in[0];
  const float* pre_w = (const float*)d_in[1];
  const float* pre_b = (const float*)d_in[2];
  const float* mix_w = (const float*)d_in[3];
  const float* mix_b = (const float*)d_in[4];
  const float* a = (const float*)d_in[5];
  const float* bfr = (const float*)d_in[6];

  // ws (176,685,056 B; ws_size >= 180,617,216 proven by round-5 guard):
  char* ws = (char*)d_ws;
  __bf16* buf0  = (__bf16*)(ws + 0);           // 67,108,864 B (x_bf -> s_bf)
  __bf16* wtbuf = (__bf16*)(ws + 67108864);    //  4,718,592 B
  __bf16* pre   = (__bf16*)(ws + 71827456);    // 69,206,016 B [16384][2112]
  float*  u     = (float*)(ws + 141033472);    //  2,097,152 B
  __bf16* z_bf  = (__bf16*)(ws + 143130624);   // 33,554,432 B [16384][1024]
  const size_t WS_NEEDED = 176685056ull;
  if (ws_size < WS_NEEDED) return;

  __bf16* x_bf = buf0;
  __bf16* s_bf = buf0;

  float* out0 = (float*)d_out;                 // f32 [16384][1024]
  float* s_re = out0 + 16777216;               // f32 Re(s)

  cvt_f32_bf16<<<16384, 256, 0, stream>>>(x, x_bf, 16777216);
  transpose_to_bf16<<<dim3(68, 32), 256, 0, stream>>>(pre_w, wtbuf, 1024, 2112, 2176);
  gemm_w2<true, 1024><<<1088, 256, 0, stream>>>(x_bf, wtbuf, pre_b, pre,
                                                2112, 2112, 17);
  u_kernel<<<256, 256, 0, stream>>>(pre, u);
  transpose_to_bf16<<<dim3(32, 64), 256, 0, stream>>>(mix_w, wtbuf, 2048, 1024, 1024);
  scan_kernel<<<128, 64, 0, stream>>>(u, a, bfr, s_bf, s_re);  // overwrites x_bf
  gemm_w2<true, 2048><<<512, 256, 0, stream>>>(s_bf, wtbuf, mix_b, z_bf,
                                               1024, 1024, 8);
  ln_gate_kernel<<<16384, 256, 0, stream>>>(z_bf, out0, pre);
}